// Round 7
// baseline (753.606 us; speedup 1.0000x reference)
//
#include <hip/hip_runtime.h>
#include <hip/hip_bf16.h>

// Sizes (fixed): B=128, M=1024, D_Z=1024, D_PHI=512, H1=512, H2=512
// ws: hzb f32[128*512] @0 (256KB) | hpb bf16[1024*512] @256K (1MB) |
//     W2F bf16[512*512] @1.25M (512KB) | W1F bf16[1536*512] @1.75M (1.5MB)
//
// Frag layout (W1F, W2F): B-fragment for (kc = k>>5, nf = n>>4) is 1024B
// contiguous: addr_ushort = (kc*32 + nf)*512 + lane*8,
//   lane = (n&15) + 16*((k>>3)&3), holds W[k..k+7][n]  (exact 16x16x32 B-frag).

typedef __bf16 bf16x8 __attribute__((ext_vector_type(8)));
typedef float  f32x4  __attribute__((ext_vector_type(4)));

// tanh-form GELU (max dev from exact erf ~5e-4)
__device__ __forceinline__ float gelu_f(float x) {
    float t = x * x;
    float inner = __builtin_fmaf(0.044715f * t, x, x);
    float e = __builtin_amdgcn_exp2f(2.3022082f * inner);
    float r = __builtin_amdgcn_rcpf(e + 1.0f);
    return __builtin_fmaf(-x, r, x);
}

__device__ __forceinline__ unsigned int pack_bf16x2(float a, float b) {
    __hip_bfloat162 h = __float22bfloat162_rn(make_float2(a, b));
    return *reinterpret_cast<unsigned int*>(&h);
}
__device__ __forceinline__ float bf_lo(unsigned int u) {
    return __builtin_bit_cast(float, u << 16);
}
__device__ __forceinline__ float bf_hi(unsigned int u) {
    return __builtin_bit_cast(float, u & 0xffff0000u);
}

// ---------------- P1: wcast — W2 (64 blocks) + W1 (192 blocks) -> frag bf16 ----------------
__global__ __launch_bounds__(256) void wcast_kernel(
    const float* __restrict__ W1, const float* __restrict__ W2,
    unsigned short* __restrict__ W1F, unsigned short* __restrict__ W2F)
{
    __shared__ float tr[64 * 68];   // 17 KB
    const int t = threadIdx.x;
    const int id = blockIdx.x;

    const float* src;
    unsigned short* dst;
    int kt, nt;
    if (id < 64) { src = W2; dst = W2F; kt = id >> 3; nt = id & 7; }
    else         { src = W1; dst = W1F; kt = (id - 64) >> 3; nt = (id - 64) & 7; }
    const int k0 = kt * 64, n0 = nt * 64;

    {
        int r = t >> 2, c16 = (t & 3) * 16;
        #pragma unroll
        for (int q = 0; q < 4; ++q)
            *(float4*)&tr[r * 68 + c16 + q * 4] =
                *(const float4*)&src[(k0 + r) * 512 + n0 + c16 + q * 4];
    }
    __syncthreads();
    const int nl = t >> 2, kc16 = (t & 3) * 16;
    unsigned int pk[8];
    #pragma unroll
    for (int i = 0; i < 8; ++i) {
        float f0 = tr[(kc16 + 2 * i    ) * 68 + nl];
        float f1 = tr[(kc16 + 2 * i + 1) * 68 + nl];
        pk[i] = pack_bf16x2(f0, f1);
    }
    const int n  = n0 + nl;
    const int nf = n >> 4;
    #pragma unroll
    for (int h = 0; h < 2; ++h) {
        int kbase = k0 + kc16 + h * 8;
        int kc = kbase >> 5;
        int k8 = (kbase >> 3) & 3;
        int lane = (n & 15) + 16 * k8;
        uint4 v = h ? make_uint4(pk[4], pk[5], pk[6], pk[7])
                    : make_uint4(pk[0], pk[1], pk[2], pk[3]);
        *(uint4*)&dst[(unsigned)((kc * 32 + nf) * 512 + lane * 8)] = v;
    }
}

// ---------------- P2: l1 — MFMA GEMM for layer 1 ----------------
// grid 18 x 512: blocks 0..1 -> hz (g_q @ W1[:1024] + b1 -> f32 hzb, K=1024)
//                blocks 2..17 -> hp (Phi @ W1[1024:] -> bf16 hpb, K=512)
__global__ __launch_bounds__(512) void l1_kernel(
    const float* __restrict__ g_q, const float* __restrict__ Phi,
    const unsigned short* __restrict__ W1F, const float* __restrict__ b1,
    float* __restrict__ hzb, unsigned short* __restrict__ hpb)
{
    __shared__ __align__(16) unsigned short lA[64 * 64];   // 8 KB

    const int t = threadIdx.x;
    const int w = t >> 6;
    const int l = t & 63;
    const int bi = blockIdx.x;
    const bool is_hz = bi < 2;
    const int r0 = is_hz ? bi * 64 : (bi - 2) * 64;
    const int ld = is_hz ? 1024 : 512;
    const int nkt = is_hz ? 16 : 8;
    const int kcb = is_hz ? 0 : 32;
    const float* src = is_hz ? g_q : Phi;

    f32x4 acc[4][4];
    #pragma unroll
    for (int a = 0; a < 4; ++a)
        #pragma unroll
        for (int bf = 0; bf < 4; ++bf)
            acc[a][bf] = f32x4{0.f, 0.f, 0.f, 0.f};

    const int arow = t >> 3;
    const int ac   = t & 7;
    const float* srow = src + (unsigned)(r0 + arow) * ld;
    const unsigned int awoff = (unsigned)(arow * 128 + ((ac ^ (arow & 7)) << 4));

    #pragma unroll 1
    for (int kt = 0; kt < nkt; ++kt) {
        uint4 breg[2][4];
        #pragma unroll
        for (int kk = 0; kk < 2; ++kk)
            #pragma unroll
            for (int bf = 0; bf < 4; ++bf)
                breg[kk][bf] = *(const uint4*)
                    &W1F[(unsigned)(((kcb + kt * 2 + kk) * 32 + w * 4 + bf) * 512 + l * 8)];

        {
            float4 p0 = *(const float4*)&srow[kt * 64 + ac * 8];
            float4 p1 = *(const float4*)&srow[kt * 64 + ac * 8 + 4];
            uint4 pk;
            pk.x = pack_bf16x2(p0.x, p0.y);
            pk.y = pack_bf16x2(p0.z, p0.w);
            pk.z = pack_bf16x2(p1.x, p1.y);
            pk.w = pack_bf16x2(p1.z, p1.w);
            *(uint4*)((char*)lA + awoff) = pk;
        }
        __syncthreads();

        #pragma unroll
        for (int kk = 0; kk < 2; ++kk) {
            const int cch = kk * 4 + (l >> 4);
            bf16x8 af[4];
            #pragma unroll
            for (int a = 0; a < 4; ++a) {
                int row = 16 * a + (l & 15);
                unsigned off = (unsigned)(row * 128 + ((cch ^ (row & 7)) << 4));
                af[a] = __builtin_bit_cast(bf16x8, *(const uint4*)((const char*)lA + off));
            }
            #pragma unroll
            for (int bf = 0; bf < 4; ++bf) {
                bf16x8 bfr = __builtin_bit_cast(bf16x8, breg[kk][bf]);
                #pragma unroll
                for (int a = 0; a < 4; ++a)
                    acc[a][bf] = __builtin_amdgcn_mfma_f32_16x16x32_bf16(
                        af[a], bfr, acc[a][bf], 0, 0, 0);
            }
        }
        __syncthreads();
    }

    const int cl = l & 15, rq = (l >> 4) * 4;
    #pragma unroll
    for (int bf = 0; bf < 4; ++bf) {
        int n = w * 64 + 16 * bf + cl;
        if (is_hz) {
            float bb = b1[n];
            #pragma unroll
            for (int a = 0; a < 4; ++a)
                #pragma unroll
                for (int r = 0; r < 4; ++r)
                    hzb[(unsigned)(r0 + 16 * a + rq + r) * 512 + n] = acc[a][bf][r] + bb;
        } else {
            #pragma unroll
            for (int a = 0; a < 4; ++a)
                #pragma unroll
                for (int r = 0; r < 4; ++r) {
                    __hip_bfloat16 v = __float2bfloat16(acc[a][bf][r]);
                    hpb[(unsigned)(r0 + 16 * a + rq + r) * 512 + n] =
                        *reinterpret_cast<unsigned short*>(&v);
                }
        }
    }
}

// ---------------- fused: gelu1 -> bf16 GEMM (x W2) -> gelu2 -> dot W3 ----------------
// Block: 256 rows x 512 cols, 1024 thr (16 waves as 4 rowgrp x 4 colgrp),
// wave tile 64x128 (acc 4x8). A (gelu1) LDS dbuf 2x32KB swizzled; B frags
// global->reg from W2F. Per kt: 16.8 MFLOP vs 64KB B-slice (4x better
// compute:B-traffic than the 64-row block). ONE barrier per kt (r4 schedule).
__global__ __launch_bounds__(1024, 4) void fused_kernel(
    const float* __restrict__ hzb, const unsigned short* __restrict__ hpb,
    const unsigned short* __restrict__ W2F,
    const float* __restrict__ b2, const float* __restrict__ W3,
    const float* __restrict__ b3, float* __restrict__ out)
{
    __shared__ __align__(16) unsigned short lA[2 * 256 * 64]; // 64 KB
    __shared__ __align__(16) float lhz[512];
    __shared__ float lred[16][64];

    const int t  = threadIdx.x;
    const int w  = t >> 6;          // 0..15
    const int l  = t & 63;
    const int rg = w >> 2;          // row group (64 rows)
    const int cg = w & 3;           // col group (128 cols)
    const int r0 = blockIdx.x * 256;
    const int b  = r0 >> 10;
    const int m0 = r0 & 1023;

    f32x4 acc[4][8];
    #pragma unroll
    for (int a = 0; a < 4; ++a)
        #pragma unroll
        for (int bf = 0; bf < 8; ++bf)
            acc[a][bf] = f32x4{0.f, 0.f, 0.f, 0.f};

    // AGEN mapping: thread -> (row = t>>2, chunks ac and ac+4)
    const int arow = t >> 2;        // 0..255
    const int ac   = t & 3;
    const unsigned short* hprow = hpb + (unsigned)(m0 + arow) * 512;
    const float4* lhz4 = (const float4*)lhz;
    const unsigned int aw0 = (unsigned)(arow * 128 + (( ac      ^ (arow & 7)) << 4));
    const unsigned int aw1 = (unsigned)(arow * 128 + (((ac + 4) ^ (arow & 7)) << 4));

    auto AGEN = [&](uint4 hvA, uint4 hvB, int kt, int buf) {
        const unsigned int bb = (unsigned)(buf * 32768);
        {
            const int kb = kt * 64 + ac * 8;
            float4 z0 = lhz4[kb >> 2];
            float4 z1 = lhz4[(kb >> 2) + 1];
            uint4 pk;
            pk.x = pack_bf16x2(gelu_f(bf_lo(hvA.x) + z0.x), gelu_f(bf_hi(hvA.x) + z0.y));
            pk.y = pack_bf16x2(gelu_f(bf_lo(hvA.y) + z0.z), gelu_f(bf_hi(hvA.y) + z0.w));
            pk.z = pack_bf16x2(gelu_f(bf_lo(hvA.z) + z1.x), gelu_f(bf_hi(hvA.z) + z1.y));
            pk.w = pack_bf16x2(gelu_f(bf_lo(hvA.w) + z1.z), gelu_f(bf_hi(hvA.w) + z1.w));
            *(uint4*)((char*)lA + bb + aw0) = pk;
        }
        {
            const int kb = kt * 64 + (ac + 4) * 8;
            float4 z0 = lhz4[kb >> 2];
            float4 z1 = lhz4[(kb >> 2) + 1];
            uint4 pk;
            pk.x = pack_bf16x2(gelu_f(bf_lo(hvB.x) + z0.x), gelu_f(bf_hi(hvB.x) + z0.y));
            pk.y = pack_bf16x2(gelu_f(bf_lo(hvB.y) + z0.z), gelu_f(bf_hi(hvB.y) + z0.w));
            pk.z = pack_bf16x2(gelu_f(bf_lo(hvB.z) + z1.x), gelu_f(bf_hi(hvB.z) + z1.y));
            pk.w = pack_bf16x2(gelu_f(bf_lo(hvB.w) + z1.z), gelu_f(bf_hi(hvB.w) + z1.w));
            *(uint4*)((char*)lA + bb + aw1) = pk;
        }
    };

    // ---- prologue ----
    if (t < 512) lhz[t] = hzb[b * 512 + t];
    uint4 hvA = *(const uint4*)&hprow[ac * 8];
    uint4 hvB = *(const uint4*)&hprow[(ac + 4) * 8];
    __syncthreads();            // lhz visible
    AGEN(hvA, hvB, 0, 0);
    __syncthreads();            // lA[0] ready

    // ---- main loop: one barrier per kt ----
    #pragma unroll 2
    for (int kt = 0; kt < 8; ++kt) {
        // B(kt) frags: 16 coalesced dwordx4 from W2F (consumed after AGEN)
        uint4 breg[2][8];
        #pragma unroll
        for (int kk = 0; kk < 2; ++kk)
            #pragma unroll
            for (int bf = 0; bf < 8; ++bf)
                breg[kk][bf] = *(const uint4*)
                    &W2F[(unsigned)(((kt * 2 + kk) * 32 + cg * 8 + bf) * 512 + l * 8)];

        // AGEN(kt+1) into other buffer (covers B latency; feeds next kt)
        if (kt < 7) {
            uint4 hA = *(const uint4*)&hprow[(kt + 1) * 64 + ac * 8];
            uint4 hB = *(const uint4*)&hprow[(kt + 1) * 64 + (ac + 4) * 8];
            AGEN(hA, hB, kt + 1, (kt + 1) & 1);
        }

        // MFMA(kt): A from lA[kt&1], B from regs
        const char* abase = (const char*)lA + (kt & 1) * 32768;
        #pragma unroll
        for (int kk = 0; kk < 2; ++kk) {
            const int cch = kk * 4 + (l >> 4);
            bf16x8 af[4];
            #pragma unroll
            for (int a = 0; a < 4; ++a) {
                int row = rg * 64 + 16 * a + (l & 15);
                unsigned off = (unsigned)(row * 128 + ((cch ^ (row & 7)) << 4));
                af[a] = __builtin_bit_cast(bf16x8, *(const uint4*)(abase + off));
            }
            #pragma unroll
            for (int bf = 0; bf < 8; ++bf) {
                bf16x8 bfr = __builtin_bit_cast(bf16x8, breg[kk][bf]);
                #pragma unroll
                for (int a = 0; a < 4; ++a)
                    acc[a][bf] = __builtin_amdgcn_mfma_f32_16x16x32_bf16(
                        af[a], bfr, acc[a][bf], 0, 0, 0);
            }
        }

        __syncthreads();        // lA[(kt+1)&1] published; lA[kt&1] free
    }

    // ---- epilogue: +b2, gelu2, dot W3, reduce ----
    float b2v[8], w3v[8];
    #pragma unroll
    for (int bf = 0; bf < 8; ++bf) {
        int n = cg * 128 + 16 * bf + (l & 15);
        b2v[bf] = b2[n];
        w3v[bf] = W3[n];
    }
    float psum[4][4];
    #pragma unroll
    for (int a = 0; a < 4; ++a)
        #pragma unroll
        for (int r = 0; r < 4; ++r) psum[a][r] = 0.f;

    #pragma unroll
    for (int bf = 0; bf < 8; ++bf)
        #pragma unroll
        for (int a = 0; a < 4; ++a)
            #pragma unroll
            for (int r = 0; r < 4; ++r) {
                float x = acc[a][bf][r] + b2v[bf];
                float h = gelu_f(x);
                psum[a][r] = __builtin_fmaf(h, w3v[bf], psum[a][r]);
            }

    #pragma unroll
    for (int a = 0; a < 4; ++a)
        #pragma unroll
        for (int r = 0; r < 4; ++r) {
            float v = psum[a][r];
            v += __shfl_xor(v, 1);
            v += __shfl_xor(v, 2);
            v += __shfl_xor(v, 4);
            v += __shfl_xor(v, 8);
            psum[a][r] = v;
        }

    if ((l & 15) == 0) {
        int gb = (l >> 4) * 4;
        #pragma unroll
        for (int a = 0; a < 4; ++a)
            #pragma unroll
            for (int r = 0; r < 4; ++r)
                lred[w][16 * a + gb + r] = psum[a][r];
    }
    __syncthreads();
    if (t < 256) {
        const int rg2 = t >> 6, rr = t & 63;
        float s = b3[0];
        #pragma unroll
        for (int c = 0; c < 4; ++c) s += lred[rg2 * 4 + c][rr];
        out[r0 + t] = s;
    }
}

extern "C" void kernel_launch(void* const* d_in, const int* in_sizes, int n_in,
                              void* d_out, int out_size, void* d_ws, size_t ws_size,
                              hipStream_t stream) {
    (void)in_sizes; (void)n_in; (void)out_size; (void)ws_size;
    const float* g_q = (const float*)d_in[0];
    const float* Phi = (const float*)d_in[1];
    const float* W1  = (const float*)d_in[2];
    const float* b1  = (const float*)d_in[3];
    const float* W2  = (const float*)d_in[4];
    const float* b2  = (const float*)d_in[5];
    const float* W3  = (const float*)d_in[6];
    const float* b3  = (const float*)d_in[7];
    float* out = (float*)d_out;

    char* ws = (char*)d_ws;
    float*          hzb = (float*)ws;                                    // 256 KB
    unsigned short* hpb = (unsigned short*)(ws + 262144);                // 1 MB
    unsigned short* W2F = (unsigned short*)(ws + 1310720);               // 512 KB
    unsigned short* W1F = (unsigned short*)(ws + 1835008);               // 1.5 MB

    hipLaunchKernelGGL(wcast_kernel, dim3(256), dim3(256), 0, stream,
                       W1, W2, W1F, W2F);
    hipLaunchKernelGGL(l1_kernel, dim3(18), dim3(512), 0, stream,
                       g_q, Phi, W1F, b1, hzb, hpb);
    hipLaunchKernelGGL(fused_kernel, dim3(512), dim3(1024), 0, stream,
                       hzb, hpb, W2F, b2, W3, b3, out);
}

// Round 8
// 120.793 us; speedup vs baseline: 6.2388x; 6.2388x over previous
//
#include <hip/hip_runtime.h>
#include <hip/hip_bf16.h>

// Sizes (fixed): B=128, M=1024, D_Z=1024, D_PHI=512, H1=512, H2=512
// ws: hzb f32[128*512] @0 (256KB) | hpb bf16[1024*512] @256K (1MB) |
//     W2F bf16[512*512] @1.25M (512KB) | W1F bf16[1536*512] @1.75M (1.5MB)
//
// Frag layout (W1F, W2F): B-fragment for (kc = k>>5, nf = n>>4) is 1024B
// contiguous: addr_ushort = (kc*32 + nf)*512 + lane*8,
//   lane = (n&15) + 16*((k>>3)&3), holds W[k..k+7][n]  (exact 16x16x32 B-frag).
//
// REGISTER BUDGET RULE (learned r7): per-SIMD VGPR pool ~512/lane; keep
// VGPR+AGPR <= 128/thread for 4 waves/SIMD. r4 sits at 64+64 = 128 exactly.

typedef __bf16 bf16x8 __attribute__((ext_vector_type(8)));
typedef float  f32x4  __attribute__((ext_vector_type(4)));

// tanh-form GELU (max dev from exact erf ~5e-4)
__device__ __forceinline__ float gelu_f(float x) {
    float t = x * x;
    float inner = __builtin_fmaf(0.044715f * t, x, x);
    float e = __builtin_amdgcn_exp2f(2.3022082f * inner);
    float r = __builtin_amdgcn_rcpf(e + 1.0f);
    return __builtin_fmaf(-x, r, x);
}

__device__ __forceinline__ unsigned int pack_bf16x2(float a, float b) {
    __hip_bfloat162 h = __float22bfloat162_rn(make_float2(a, b));
    return *reinterpret_cast<unsigned int*>(&h);
}
__device__ __forceinline__ float bf_lo(unsigned int u) {
    return __builtin_bit_cast(float, u << 16);
}
__device__ __forceinline__ float bf_hi(unsigned int u) {
    return __builtin_bit_cast(float, u & 0xffff0000u);
}

// ---------------- P1: wcast — W2 (64 blocks) + W1 (192 blocks) -> frag bf16 ----------------
__global__ __launch_bounds__(256) void wcast_kernel(
    const float* __restrict__ W1, const float* __restrict__ W2,
    unsigned short* __restrict__ W1F, unsigned short* __restrict__ W2F)
{
    __shared__ float tr[64 * 68];   // 17 KB
    const int t = threadIdx.x;
    const int id = blockIdx.x;

    const float* src;
    unsigned short* dst;
    int kt, nt;
    if (id < 64) { src = W2; dst = W2F; kt = id >> 3; nt = id & 7; }
    else         { src = W1; dst = W1F; kt = (id - 64) >> 3; nt = (id - 64) & 7; }
    const int k0 = kt * 64, n0 = nt * 64;

    {
        int r = t >> 2, c16 = (t & 3) * 16;
        #pragma unroll
        for (int q = 0; q < 4; ++q)
            *(float4*)&tr[r * 68 + c16 + q * 4] =
                *(const float4*)&src[(k0 + r) * 512 + n0 + c16 + q * 4];
    }
    __syncthreads();
    const int nl = t >> 2, kc16 = (t & 3) * 16;
    unsigned int pk[8];
    #pragma unroll
    for (int i = 0; i < 8; ++i) {
        float f0 = tr[(kc16 + 2 * i    ) * 68 + nl];
        float f1 = tr[(kc16 + 2 * i + 1) * 68 + nl];
        pk[i] = pack_bf16x2(f0, f1);
    }
    const int n  = n0 + nl;
    const int nf = n >> 4;
    #pragma unroll
    for (int h = 0; h < 2; ++h) {
        int kbase = k0 + kc16 + h * 8;
        int kc = kbase >> 5;
        int k8 = (kbase >> 3) & 3;
        int lane = (n & 15) + 16 * k8;
        uint4 v = h ? make_uint4(pk[4], pk[5], pk[6], pk[7])
                    : make_uint4(pk[0], pk[1], pk[2], pk[3]);
        *(uint4*)&dst[(unsigned)((kc * 32 + nf) * 512 + lane * 8)] = v;
    }
}

// ---------------- P2: l1 — MFMA GEMM for layer 1 ----------------
// grid 18 x 512: blocks 0..1 -> hz (g_q @ W1[:1024] + b1 -> f32 hzb, K=1024)
//                blocks 2..17 -> hp (Phi @ W1[1024:] -> bf16 hpb, K=512)
__global__ __launch_bounds__(512) void l1_kernel(
    const float* __restrict__ g_q, const float* __restrict__ Phi,
    const unsigned short* __restrict__ W1F, const float* __restrict__ b1,
    float* __restrict__ hzb, unsigned short* __restrict__ hpb)
{
    __shared__ __align__(16) unsigned short lA[64 * 64];   // 8 KB

    const int t = threadIdx.x;
    const int w = t >> 6;
    const int l = t & 63;
    const int bi = blockIdx.x;
    const bool is_hz = bi < 2;
    const int r0 = is_hz ? bi * 64 : (bi - 2) * 64;
    const int ld = is_hz ? 1024 : 512;
    const int nkt = is_hz ? 16 : 8;
    const int kcb = is_hz ? 0 : 32;
    const float* src = is_hz ? g_q : Phi;

    f32x4 acc[4][4];
    #pragma unroll
    for (int a = 0; a < 4; ++a)
        #pragma unroll
        for (int bf = 0; bf < 4; ++bf)
            acc[a][bf] = f32x4{0.f, 0.f, 0.f, 0.f};

    const int arow = t >> 3;
    const int ac   = t & 7;
    const float* srow = src + (unsigned)(r0 + arow) * ld;
    const unsigned int awoff = (unsigned)(arow * 128 + ((ac ^ (arow & 7)) << 4));

    #pragma unroll 1
    for (int kt = 0; kt < nkt; ++kt) {
        uint4 breg[2][4];
        #pragma unroll
        for (int kk = 0; kk < 2; ++kk)
            #pragma unroll
            for (int bf = 0; bf < 4; ++bf)
                breg[kk][bf] = *(const uint4*)
                    &W1F[(unsigned)(((kcb + kt * 2 + kk) * 32 + w * 4 + bf) * 512 + l * 8)];

        {
            float4 p0 = *(const float4*)&srow[kt * 64 + ac * 8];
            float4 p1 = *(const float4*)&srow[kt * 64 + ac * 8 + 4];
            uint4 pk;
            pk.x = pack_bf16x2(p0.x, p0.y);
            pk.y = pack_bf16x2(p0.z, p0.w);
            pk.z = pack_bf16x2(p1.x, p1.y);
            pk.w = pack_bf16x2(p1.z, p1.w);
            *(uint4*)((char*)lA + awoff) = pk;
        }
        __syncthreads();

        #pragma unroll
        for (int kk = 0; kk < 2; ++kk) {
            const int cch = kk * 4 + (l >> 4);
            bf16x8 af[4];
            #pragma unroll
            for (int a = 0; a < 4; ++a) {
                int row = 16 * a + (l & 15);
                unsigned off = (unsigned)(row * 128 + ((cch ^ (row & 7)) << 4));
                af[a] = __builtin_bit_cast(bf16x8, *(const uint4*)((const char*)lA + off));
            }
            #pragma unroll
            for (int bf = 0; bf < 4; ++bf) {
                bf16x8 bfr = __builtin_bit_cast(bf16x8, breg[kk][bf]);
                #pragma unroll
                for (int a = 0; a < 4; ++a)
                    acc[a][bf] = __builtin_amdgcn_mfma_f32_16x16x32_bf16(
                        af[a], bfr, acc[a][bf], 0, 0, 0);
            }
        }
        __syncthreads();
    }

    const int cl = l & 15, rq = (l >> 4) * 4;
    #pragma unroll
    for (int bf = 0; bf < 4; ++bf) {
        int n = w * 64 + 16 * bf + cl;
        if (is_hz) {
            float bb = b1[n];
            #pragma unroll
            for (int a = 0; a < 4; ++a)
                #pragma unroll
                for (int r = 0; r < 4; ++r)
                    hzb[(unsigned)(r0 + 16 * a + rq + r) * 512 + n] = acc[a][bf][r] + bb;
        } else {
            #pragma unroll
            for (int a = 0; a < 4; ++a)
                #pragma unroll
                for (int r = 0; r < 4; ++r) {
                    __hip_bfloat16 v = __float2bfloat16(acc[a][bf][r]);
                    hpb[(unsigned)(r0 + 16 * a + rq + r) * 512 + n] =
                        *reinterpret_cast<unsigned short*>(&v);
                }
        }
    }
}

// ---------------- fused: gelu1 -> bf16 GEMM (x W2) -> gelu2 -> dot W3 ----------------
// r4 structure (64r x 512c, 8 waves, wave 64x64, acc 4x4, one barrier/kt,
// B frags global->reg) + ONE change: hp slices prefetched 2 kt ahead into a
// 2x8KB LDS ring via global_load_lds (zero VGPR cost, full-body latency cover).
// LDS dest = wave-uniform base + lane*16 (G21-compliant); AGEN reads back its
// own 16B (identity mapping both sides).
__global__ __launch_bounds__(512, 2) void fused_kernel(
    const float* __restrict__ hzb, const unsigned short* __restrict__ hpb,
    const unsigned short* __restrict__ W2F,
    const float* __restrict__ b2, const float* __restrict__ W3,
    const float* __restrict__ b3, float* __restrict__ out)
{
    __shared__ __align__(16) unsigned short lA[2 * 64 * 64];      // 16 KB
    __shared__ __align__(16) unsigned short hstage[2 * 64 * 64];  // 16 KB
    __shared__ __align__(16) float lhz[512];
    __shared__ float lred[8][64];

    const int t = threadIdx.x;
    const int w = __builtin_amdgcn_readfirstlane(t >> 6);  // wave id, SGPR
    const int l = t & 63;
    const int r0 = blockIdx.x * 64;
    const int b  = r0 >> 10;
    const int m0 = r0 & 1023;

    f32x4 acc[4][4];
    #pragma unroll
    for (int a = 0; a < 4; ++a)
        #pragma unroll
        for (int bf = 0; bf < 4; ++bf)
            acc[a][bf] = f32x4{0.f, 0.f, 0.f, 0.f};

    const int arow = t >> 3;
    const int ac   = t & 7;
    const unsigned short* hprow = hpb + (unsigned)(m0 + arow) * 512;
    const float4* lhz4 = (const float4*)lhz;
    const unsigned int awoff = (unsigned)(arow * 128 + ((ac ^ (arow & 7)) << 4));
    const unsigned int hoff  = (unsigned)(t * 16);   // byte offset in hstage buf

    // stage hp(kt) slice into hstage[buf]: 512 threads x 16B = 8KB
    auto HPSTAGE = [&](int kt, int buf) {
        __builtin_amdgcn_global_load_lds(
            (const __attribute__((address_space(1))) void*)(hprow + kt * 64 + ac * 8),
            (__attribute__((address_space(3))) void*)((char*)hstage + buf * 8192 + hoff),
            16, 0, 0);
    };

    auto AGEN = [&](int kt, int abuf) {
        uint4 hv = *(const uint4*)((const char*)hstage + (kt & 1) * 8192 + hoff);
        const int kb = kt * 64 + ac * 8;
        float4 z0 = lhz4[kb >> 2];
        float4 z1 = lhz4[(kb >> 2) + 1];
        float g0 = gelu_f(bf_lo(hv.x) + z0.x);
        float g1 = gelu_f(bf_hi(hv.x) + z0.y);
        float g2 = gelu_f(bf_lo(hv.y) + z0.z);
        float g3 = gelu_f(bf_hi(hv.y) + z0.w);
        float g4 = gelu_f(bf_lo(hv.z) + z1.x);
        float g5 = gelu_f(bf_hi(hv.z) + z1.y);
        float g6 = gelu_f(bf_lo(hv.w) + z1.z);
        float g7 = gelu_f(bf_hi(hv.w) + z1.w);
        uint4 pk;
        pk.x = pack_bf16x2(g0, g1);
        pk.y = pack_bf16x2(g2, g3);
        pk.z = pack_bf16x2(g4, g5);
        pk.w = pack_bf16x2(g6, g7);
        *(uint4*)((char*)lA + (unsigned)(abuf * 8192) + awoff) = pk;
    };

    // ---- prologue ----
    HPSTAGE(0, 0);
    HPSTAGE(1, 1);
    lhz[t] = hzb[b * 512 + t];
    __syncthreads();            // vmcnt drain: hstage0/1 + lhz ready
    AGEN(0, 0);
    __syncthreads();            // lA[0] ready

    // ---- main loop: one barrier per kt ----
    #pragma unroll 2
    for (int kt = 0; kt < 8; ++kt) {
        // prefetch hp(kt+2) into the hstage buf AGEN(kt) released last body
        if (kt < 6) HPSTAGE(kt + 2, kt & 1);

        // B(kt) frags: 8 coalesced dwordx4 (SGPR-based addr; consumed after AGEN)
        uint4 breg[2][4];
        #pragma unroll
        for (int kk = 0; kk < 2; ++kk)
            #pragma unroll
            for (int bf = 0; bf < 4; ++bf)
                breg[kk][bf] = *(const uint4*)
                    &W2F[(unsigned)(((kt * 2 + kk) * 32 + w * 4 + bf) * 512 + l * 8)];

        // AGEN(kt+1) from LDS-staged hp (covers B latency; feeds next kt)
        if (kt < 7) AGEN(kt + 1, (kt + 1) & 1);

        // MFMA(kt): A from lA[kt&1], B from regs
        const char* abase = (const char*)lA + (kt & 1) * 8192;
        #pragma unroll
        for (int kk = 0; kk < 2; ++kk) {
            const int cch = kk * 4 + (l >> 4);
            bf16x8 af[4];
            #pragma unroll
            for (int a = 0; a < 4; ++a) {
                int row = 16 * a + (l & 15);
                unsigned off = (unsigned)(row * 128 + ((cch ^ (row & 7)) << 4));
                af[a] = __builtin_bit_cast(bf16x8, *(const uint4*)(abase + off));
            }
            #pragma unroll
            for (int bf = 0; bf < 4; ++bf) {
                bf16x8 bfr = __builtin_bit_cast(bf16x8, breg[kk][bf]);
                #pragma unroll
                for (int a = 0; a < 4; ++a)
                    acc[a][bf] = __builtin_amdgcn_mfma_f32_16x16x32_bf16(
                        af[a], bfr, acc[a][bf], 0, 0, 0);
            }
        }

        __syncthreads();        // publishes lA[(kt+1)&1]; drains HPSTAGE(kt+2)
    }

    // ---- epilogue: +b2, gelu2, dot W3, reduce ----
    float b2v[4], w3v[4];
    #pragma unroll
    for (int bf = 0; bf < 4; ++bf) {
        int n = w * 64 + 16 * bf + (l & 15);
        b2v[bf] = b2[n];
        w3v[bf] = W3[n];
    }
    float psum[4][4];
    #pragma unroll
    for (int a = 0; a < 4; ++a)
        #pragma unroll
        for (int r = 0; r < 4; ++r) psum[a][r] = 0.f;

    #pragma unroll
    for (int bf = 0; bf < 4; ++bf)
        #pragma unroll
        for (int a = 0; a < 4; ++a)
            #pragma unroll
            for (int r = 0; r < 4; ++r) {
                float x = acc[a][bf][r] + b2v[bf];
                float h = gelu_f(x);
                psum[a][r] = __builtin_fmaf(h, w3v[bf], psum[a][r]);
            }

    #pragma unroll
    for (int a = 0; a < 4; ++a)
        #pragma unroll
        for (int r = 0; r < 4; ++r) {
            float v = psum[a][r];
            v += __shfl_xor(v, 1);
            v += __shfl_xor(v, 2);
            v += __shfl_xor(v, 4);
            v += __shfl_xor(v, 8);
            psum[a][r] = v;
        }

    if ((l & 15) == 0) {
        int gb = (l >> 4) * 4;
        #pragma unroll
        for (int a = 0; a < 4; ++a)
            #pragma unroll
            for (int r = 0; r < 4; ++r)
                lred[w][16 * a + gb + r] = psum[a][r];
    }
    __syncthreads();
    if (t < 64) {
        float s = b3[0];
        #pragma unroll
        for (int ww = 0; ww < 8; ++ww) s += lred[ww][t];
        out[r0 + t] = s;
    }
}

extern "C" void kernel_launch(void* const* d_in, const int* in_sizes, int n_in,
                              void* d_out, int out_size, void* d_ws, size_t ws_size,
                              hipStream_t stream) {
    (void)in_sizes; (void)n_in; (void)out_size; (void)ws_size;
    const float* g_q = (const float*)d_in[0];
    const float* Phi = (const float*)d_in[1];
    const float* W1  = (const float*)d_in[2];
    const float* b1  = (const float*)d_in[3];
    const float* W2  = (const float*)d_in[4];
    const float* b2  = (const float*)d_in[5];
    const float* W3  = (const float*)d_in[6];
    const float* b3  = (const float*)d_in[7];
    float* out = (float*)d_out;

    char* ws = (char*)d_ws;
    float*          hzb = (float*)ws;                                    // 256 KB
    unsigned short* hpb = (unsigned short*)(ws + 262144);                // 1 MB
    unsigned short* W2F = (unsigned short*)(ws + 1310720);               // 512 KB
    unsigned short* W1F = (unsigned short*)(ws + 1835008);               // 1.5 MB

    hipLaunchKernelGGL(wcast_kernel, dim3(256), dim3(256), 0, stream,
                       W1, W2, W1F, W2F);
    hipLaunchKernelGGL(l1_kernel, dim3(18), dim3(512), 0, stream,
                       g_q, Phi, W1F, b1, hzb, hpb);
    hipLaunchKernelGGL(fused_kernel, dim3(2048), dim3(512), 0, stream,
                       hzb, hpb, W2F, b2, W3, b3, out);
}

// Round 9
// 115.507 us; speedup vs baseline: 6.5243x; 1.0458x over previous
//
#include <hip/hip_runtime.h>
#include <hip/hip_bf16.h>

// Sizes (fixed): B=128, M=1024, D_Z=1024, D_PHI=512, H1=512, H2=512
// ws: hzb f32[128*512] @0 (256KB) | hpb bf16[1024*512] @256K (1MB) |
//     W2F bf16[512*512] @1.25M (512KB) | W1F bf16[1536*512] @1.75M (1.5MB)
//
// Frag layout (W1F, W2F): B-fragment for (kc = k>>5, nf = n>>4) is 1024B
// contiguous: addr_ushort = (kc*32 + nf)*512 + lane*8,
//   lane = (n&15) + 16*((k>>3)&3), holds W[k..k+7][n]  (exact 16x16x32 B-frag).
//
// REGISTER BUDGET RULE (r7): keep VGPR+AGPR <= 128/thread for 4 waves/SIMD.
// VALU RULE (r8): kernel is gelu-VALU-issue-bound -> use packed fp32 (v_pk_*).

typedef __bf16 bf16x8 __attribute__((ext_vector_type(8)));
typedef float  f32x4  __attribute__((ext_vector_type(4)));
typedef float  f32x2  __attribute__((ext_vector_type(2)));

// tanh-form GELU, packed pair. exp2(x*(c1 + c3*x^2)) identical to
// exp2(2.3022082*(x + 0.044715 x^3)); c3 = 2.3022082*0.044715.
__device__ __forceinline__ f32x2 gelu_pk(f32x2 x) {
    f32x2 t = x * x;
    f32x2 p = __builtin_elementwise_fma(t, f32x2{0.1029436f, 0.1029436f},
                                        f32x2{2.3022082f, 2.3022082f});
    f32x2 a = p * x;
    f32x2 e;
    e.x = __builtin_amdgcn_exp2f(a.x);
    e.y = __builtin_amdgcn_exp2f(a.y);
    f32x2 d = e + f32x2{1.f, 1.f};
    f32x2 r;
    r.x = __builtin_amdgcn_rcpf(d.x);
    r.y = __builtin_amdgcn_rcpf(d.y);
    return __builtin_elementwise_fma(-x, r, x);   // x - x*r
}

__device__ __forceinline__ unsigned int pack_bf16x2(float a, float b) {
    __hip_bfloat162 h = __float22bfloat162_rn(make_float2(a, b));
    return *reinterpret_cast<unsigned int*>(&h);
}
__device__ __forceinline__ float bf_lo(unsigned int u) {
    return __builtin_bit_cast(float, u << 16);
}
__device__ __forceinline__ float bf_hi(unsigned int u) {
    return __builtin_bit_cast(float, u & 0xffff0000u);
}

// ---------------- P1: wcast — W2 (64 blocks) + W1 (192 blocks) -> frag bf16 ----------------
__global__ __launch_bounds__(256) void wcast_kernel(
    const float* __restrict__ W1, const float* __restrict__ W2,
    unsigned short* __restrict__ W1F, unsigned short* __restrict__ W2F)
{
    __shared__ float tr[64 * 68];   // 17 KB
    const int t = threadIdx.x;
    const int id = blockIdx.x;

    const float* src;
    unsigned short* dst;
    int kt, nt;
    if (id < 64) { src = W2; dst = W2F; kt = id >> 3; nt = id & 7; }
    else         { src = W1; dst = W1F; kt = (id - 64) >> 3; nt = (id - 64) & 7; }
    const int k0 = kt * 64, n0 = nt * 64;

    {
        int r = t >> 2, c16 = (t & 3) * 16;
        #pragma unroll
        for (int q = 0; q < 4; ++q)
            *(float4*)&tr[r * 68 + c16 + q * 4] =
                *(const float4*)&src[(k0 + r) * 512 + n0 + c16 + q * 4];
    }
    __syncthreads();
    const int nl = t >> 2, kc16 = (t & 3) * 16;
    unsigned int pk[8];
    #pragma unroll
    for (int i = 0; i < 8; ++i) {
        float f0 = tr[(kc16 + 2 * i    ) * 68 + nl];
        float f1 = tr[(kc16 + 2 * i + 1) * 68 + nl];
        pk[i] = pack_bf16x2(f0, f1);
    }
    const int n  = n0 + nl;
    const int nf = n >> 4;
    #pragma unroll
    for (int h = 0; h < 2; ++h) {
        int kbase = k0 + kc16 + h * 8;
        int kc = kbase >> 5;
        int k8 = (kbase >> 3) & 3;
        int lane = (n & 15) + 16 * k8;
        uint4 v = h ? make_uint4(pk[4], pk[5], pk[6], pk[7])
                    : make_uint4(pk[0], pk[1], pk[2], pk[3]);
        *(uint4*)&dst[(unsigned)((kc * 32 + nf) * 512 + lane * 8)] = v;
    }
}

// ---------------- P2: l1 — MFMA GEMM for layer 1 ----------------
// grid 18 x 512: blocks 0..1 -> hz (g_q @ W1[:1024] + b1 -> f32 hzb, K=1024)
//                blocks 2..17 -> hp (Phi @ W1[1024:] -> bf16 hpb, K=512)
__global__ __launch_bounds__(512) void l1_kernel(
    const float* __restrict__ g_q, const float* __restrict__ Phi,
    const unsigned short* __restrict__ W1F, const float* __restrict__ b1,
    float* __restrict__ hzb, unsigned short* __restrict__ hpb)
{
    __shared__ __align__(16) unsigned short lA[64 * 64];   // 8 KB

    const int t = threadIdx.x;
    const int w = t >> 6;
    const int l = t & 63;
    const int bi = blockIdx.x;
    const bool is_hz = bi < 2;
    const int r0 = is_hz ? bi * 64 : (bi - 2) * 64;
    const int ld = is_hz ? 1024 : 512;
    const int nkt = is_hz ? 16 : 8;
    const int kcb = is_hz ? 0 : 32;
    const float* src = is_hz ? g_q : Phi;

    f32x4 acc[4][4];
    #pragma unroll
    for (int a = 0; a < 4; ++a)
        #pragma unroll
        for (int bf = 0; bf < 4; ++bf)
            acc[a][bf] = f32x4{0.f, 0.f, 0.f, 0.f};

    const int arow = t >> 3;
    const int ac   = t & 7;
    const float* srow = src + (unsigned)(r0 + arow) * ld;
    const unsigned int awoff = (unsigned)(arow * 128 + ((ac ^ (arow & 7)) << 4));

    #pragma unroll 1
    for (int kt = 0; kt < nkt; ++kt) {
        uint4 breg[2][4];
        #pragma unroll
        for (int kk = 0; kk < 2; ++kk)
            #pragma unroll
            for (int bf = 0; bf < 4; ++bf)
                breg[kk][bf] = *(const uint4*)
                    &W1F[(unsigned)(((kcb + kt * 2 + kk) * 32 + w * 4 + bf) * 512 + l * 8)];

        {
            float4 p0 = *(const float4*)&srow[kt * 64 + ac * 8];
            float4 p1 = *(const float4*)&srow[kt * 64 + ac * 8 + 4];
            uint4 pk;
            pk.x = pack_bf16x2(p0.x, p0.y);
            pk.y = pack_bf16x2(p0.z, p0.w);
            pk.z = pack_bf16x2(p1.x, p1.y);
            pk.w = pack_bf16x2(p1.z, p1.w);
            *(uint4*)((char*)lA + awoff) = pk;
        }
        __syncthreads();

        #pragma unroll
        for (int kk = 0; kk < 2; ++kk) {
            const int cch = kk * 4 + (l >> 4);
            bf16x8 af[4];
            #pragma unroll
            for (int a = 0; a < 4; ++a) {
                int row = 16 * a + (l & 15);
                unsigned off = (unsigned)(row * 128 + ((cch ^ (row & 7)) << 4));
                af[a] = __builtin_bit_cast(bf16x8, *(const uint4*)((const char*)lA + off));
            }
            #pragma unroll
            for (int bf = 0; bf < 4; ++bf) {
                bf16x8 bfr = __builtin_bit_cast(bf16x8, breg[kk][bf]);
                #pragma unroll
                for (int a = 0; a < 4; ++a)
                    acc[a][bf] = __builtin_amdgcn_mfma_f32_16x16x32_bf16(
                        af[a], bfr, acc[a][bf], 0, 0, 0);
            }
        }
        __syncthreads();
    }

    const int cl = l & 15, rq = (l >> 4) * 4;
    #pragma unroll
    for (int bf = 0; bf < 4; ++bf) {
        int n = w * 64 + 16 * bf + cl;
        if (is_hz) {
            float bb = b1[n];
            #pragma unroll
            for (int a = 0; a < 4; ++a)
                #pragma unroll
                for (int r = 0; r < 4; ++r)
                    hzb[(unsigned)(r0 + 16 * a + rq + r) * 512 + n] = acc[a][bf][r] + bb;
        } else {
            #pragma unroll
            for (int a = 0; a < 4; ++a)
                #pragma unroll
                for (int r = 0; r < 4; ++r) {
                    __hip_bfloat16 v = __float2bfloat16(acc[a][bf][r]);
                    hpb[(unsigned)(r0 + 16 * a + rq + r) * 512 + n] =
                        *reinterpret_cast<unsigned short*>(&v);
                }
        }
    }
}

// ---------------- fused: gelu1 -> bf16 GEMM (x W2) -> gelu2 -> dot W3 ----------------
// r8 structure (64r x 512c, 8 waves, wave 64x64, acc 4x4, one barrier/kt,
// B frags global->reg, hp via 2x8KB global_load_lds ring) + packed-fp32 gelu.
__global__ __launch_bounds__(512, 2) void fused_kernel(
    const float* __restrict__ hzb, const unsigned short* __restrict__ hpb,
    const unsigned short* __restrict__ W2F,
    const float* __restrict__ b2, const float* __restrict__ W3,
    const float* __restrict__ b3, float* __restrict__ out)
{
    __shared__ __align__(16) unsigned short lA[2 * 64 * 64];      // 16 KB
    __shared__ __align__(16) unsigned short hstage[2 * 64 * 64];  // 16 KB
    __shared__ __align__(16) float lhz[512];
    __shared__ float lred[8][64];

    const int t = threadIdx.x;
    const int w = __builtin_amdgcn_readfirstlane(t >> 6);  // wave id, SGPR
    const int l = t & 63;
    const int r0 = blockIdx.x * 64;
    const int b  = r0 >> 10;
    const int m0 = r0 & 1023;

    f32x4 acc[4][4];
    #pragma unroll
    for (int a = 0; a < 4; ++a)
        #pragma unroll
        for (int bf = 0; bf < 4; ++bf)
            acc[a][bf] = f32x4{0.f, 0.f, 0.f, 0.f};

    const int arow = t >> 3;
    const int ac   = t & 7;
    const unsigned short* hprow = hpb + (unsigned)(m0 + arow) * 512;
    const float4* lhz4 = (const float4*)lhz;
    const unsigned int awoff = (unsigned)(arow * 128 + ((ac ^ (arow & 7)) << 4));
    const unsigned int hoff  = (unsigned)(t * 16);

    auto HPSTAGE = [&](int kt, int buf) {
        __builtin_amdgcn_global_load_lds(
            (const __attribute__((address_space(1))) void*)(hprow + kt * 64 + ac * 8),
            (__attribute__((address_space(3))) void*)((char*)hstage + buf * 8192 + hoff),
            16, 0, 0);
    };

    auto AGEN = [&](int kt, int abuf) {
        uint4 hv = *(const uint4*)((const char*)hstage + (kt & 1) * 8192 + hoff);
        const int kb = kt * 64 + ac * 8;
        float4 z0 = lhz4[kb >> 2];
        float4 z1 = lhz4[(kb >> 2) + 1];
        f32x2 g0 = gelu_pk(f32x2{bf_lo(hv.x), bf_hi(hv.x)} + f32x2{z0.x, z0.y});
        f32x2 g1 = gelu_pk(f32x2{bf_lo(hv.y), bf_hi(hv.y)} + f32x2{z0.z, z0.w});
        f32x2 g2 = gelu_pk(f32x2{bf_lo(hv.z), bf_hi(hv.z)} + f32x2{z1.x, z1.y});
        f32x2 g3 = gelu_pk(f32x2{bf_lo(hv.w), bf_hi(hv.w)} + f32x2{z1.z, z1.w});
        uint4 pk;
        pk.x = pack_bf16x2(g0.x, g0.y);
        pk.y = pack_bf16x2(g1.x, g1.y);
        pk.z = pack_bf16x2(g2.x, g2.y);
        pk.w = pack_bf16x2(g3.x, g3.y);
        *(uint4*)((char*)lA + (unsigned)(abuf * 8192) + awoff) = pk;
    };

    // ---- prologue ----
    HPSTAGE(0, 0);
    HPSTAGE(1, 1);
    lhz[t] = hzb[b * 512 + t];
    __syncthreads();            // vmcnt drain: hstage0/1 + lhz ready
    AGEN(0, 0);
    __syncthreads();            // lA[0] ready

    // ---- main loop: one barrier per kt ----
    #pragma unroll 2
    for (int kt = 0; kt < 8; ++kt) {
        if (kt < 6) HPSTAGE(kt + 2, kt & 1);

        uint4 breg[2][4];
        #pragma unroll
        for (int kk = 0; kk < 2; ++kk)
            #pragma unroll
            for (int bf = 0; bf < 4; ++bf)
                breg[kk][bf] = *(const uint4*)
                    &W2F[(unsigned)(((kt * 2 + kk) * 32 + w * 4 + bf) * 512 + l * 8)];

        if (kt < 7) AGEN(kt + 1, (kt + 1) & 1);

        const char* abase = (const char*)lA + (kt & 1) * 8192;
        #pragma unroll
        for (int kk = 0; kk < 2; ++kk) {
            const int cch = kk * 4 + (l >> 4);
            bf16x8 af[4];
            #pragma unroll
            for (int a = 0; a < 4; ++a) {
                int row = 16 * a + (l & 15);
                unsigned off = (unsigned)(row * 128 + ((cch ^ (row & 7)) << 4));
                af[a] = __builtin_bit_cast(bf16x8, *(const uint4*)(abase + off));
            }
            #pragma unroll
            for (int bf = 0; bf < 4; ++bf) {
                bf16x8 bfr = __builtin_bit_cast(bf16x8, breg[kk][bf]);
                #pragma unroll
                for (int a = 0; a < 4; ++a)
                    acc[a][bf] = __builtin_amdgcn_mfma_f32_16x16x32_bf16(
                        af[a], bfr, acc[a][bf], 0, 0, 0);
            }
        }

        __syncthreads();
    }

    // ---- epilogue: +b2, gelu2 (packed), dot W3, reduce ----
    float b2v[4], w3v[4];
    #pragma unroll
    for (int bf = 0; bf < 4; ++bf) {
        int n = w * 64 + 16 * bf + (l & 15);
        b2v[bf] = b2[n];
        w3v[bf] = W3[n];
    }
    f32x2 ps[4][2];
    #pragma unroll
    for (int a = 0; a < 4; ++a) {
        ps[a][0] = f32x2{0.f, 0.f};
        ps[a][1] = f32x2{0.f, 0.f};
    }

    #pragma unroll
    for (int bf = 0; bf < 4; ++bf) {
        const f32x2 b2p = {b2v[bf], b2v[bf]};
        const f32x2 w3p = {w3v[bf], w3v[bf]};
        #pragma unroll
        for (int a = 0; a < 4; ++a) {
            f32x2 xlo = f32x2{acc[a][bf][0], acc[a][bf][1]} + b2p;
            f32x2 xhi = f32x2{acc[a][bf][2], acc[a][bf][3]} + b2p;
            ps[a][0] = __builtin_elementwise_fma(gelu_pk(xlo), w3p, ps[a][0]);
            ps[a][1] = __builtin_elementwise_fma(gelu_pk(xhi), w3p, ps[a][1]);
        }
    }

    float psum[4][4];
    #pragma unroll
    for (int a = 0; a < 4; ++a) {
        psum[a][0] = ps[a][0].x; psum[a][1] = ps[a][0].y;
        psum[a][2] = ps[a][1].x; psum[a][3] = ps[a][1].y;
    }

    #pragma unroll
    for (int a = 0; a < 4; ++a)
        #pragma unroll
        for (int r = 0; r < 4; ++r) {
            float v = psum[a][r];
            v += __shfl_xor(v, 1);
            v += __shfl_xor(v, 2);
            v += __shfl_xor(v, 4);
            v += __shfl_xor(v, 8);
            psum[a][r] = v;
        }

    if ((l & 15) == 0) {
        int gb = (l >> 4) * 4;
        #pragma unroll
        for (int a = 0; a < 4; ++a)
            #pragma unroll
            for (int r = 0; r < 4; ++r)
                lred[w][16 * a + gb + r] = psum[a][r];
    }
    __syncthreads();
    if (t < 64) {
        float s = b3[0];
        #pragma unroll
        for (int ww = 0; ww < 8; ++ww) s += lred[ww][t];
        out[r0 + t] = s;
    }
}

extern "C" void kernel_launch(void* const* d_in, const int* in_sizes, int n_in,
                              void* d_out, int out_size, void* d_ws, size_t ws_size,
                              hipStream_t stream) {
    (void)in_sizes; (void)n_in; (void)out_size; (void)ws_size;
    const float* g_q = (const float*)d_in[0];
    const float* Phi = (const float*)d_in[1];
    const float* W1  = (const float*)d_in[2];
    const float* b1  = (const float*)d_in[3];
    const float* W2  = (const float*)d_in[4];
    const float* b2  = (const float*)d_in[5];
    const float* W3  = (const float*)d_in[6];
    const float* b3  = (const float*)d_in[7];
    float* out = (float*)d_out;

    char* ws = (char*)d_ws;
    float*          hzb = (float*)ws;                                    // 256 KB
    unsigned short* hpb = (unsigned short*)(ws + 262144);                // 1 MB
    unsigned short* W2F = (unsigned short*)(ws + 1310720);               // 512 KB
    unsigned short* W1F = (unsigned short*)(ws + 1835008);               // 1.5 MB

    hipLaunchKernelGGL(wcast_kernel, dim3(256), dim3(256), 0, stream,
                       W1, W2, W1F, W2F);
    hipLaunchKernelGGL(l1_kernel, dim3(18), dim3(512), 0, stream,
                       g_q, Phi, W1F, b1, hzb, hpb);
    hipLaunchKernelGGL(fused_kernel, dim3(2048), dim3(512), 0, stream,
                       hzb, hpb, W2F, b2, W3, b3, out);
}